// Round 1
// 419.458 us; speedup vs baseline: 1.2134x; 1.2134x over previous
//
#include <hip/hip_runtime.h>

// Cost volume: out[b, dy*9+dx, h, w] = leaky( mean_c c1[b,c,h,w] * warped[b,c,h+dy-4,w+dx-4] )
// B=8 C=192 H=128 W=160, 81 offsets, fp32, zero-padded borders.
//
// R4: remove LDS + all barriers. The previous double-buffered LDS pipeline was
// 83% stall (VALUBusy 16.8%): 48 block-wide barriers serialized 6 waves behind
// vmcnt(0) drains, with only 2 barrier-locked blocks/CU to overlap. The warped
// window per channel (~26KB) is L1-resident anyway, and c1 reads across the 9
// dy-groups are same-address (coalescer dedups), so LDS sharing is not needed.
//
// New structure: 1 thread = (b, h, dy, w-group of 8). Per channel it loads its
// 16-float warped window (4 aligned dwordx4: w0-4 is 16B-aligned since
// 4*(w0-4) = 32g-16) and 8 c1 floats (2 dwordx4), does 72 FMAs with full
// in-register dx-reuse, and prefetches the next channel's loads under the
// current FMAs. No syncthreads, no LDS -> waves slip freely; latency hidden by
// 3-4 waves/SIMD of independent work.
//
// Edges: W handled by clamping the first/last load column for g==0/g==19 and
// multiplying those 4-float groups by a 0/1 mask. H handled by clamping the
// row address; an out-of-range warped row makes the entire (dy) output row
// exactly 0 (reference zero-pads), so the epilogue writes zeros for it.

namespace {
constexpr int SR  = 4;
constexpr int MO  = 9;               // 2*SR+1
constexpr int NB  = 8;
constexpr int NC  = 192;
constexpr int NH  = 128;
constexpr int NW  = 160;
constexpr int HW  = NH * NW;
constexpr int WPT = 8;               // w pixels per thread
constexpr int NG  = NW / WPT;        // 20 w-groups
constexpr int UPH = MO * NG;         // 180 work units per (b,h)
constexpr int NT  = 256;
constexpr int TOTAL = NB * NH * UPH; // 184320 threads
constexpr int NBLK  = TOTAL / NT;    // 720 blocks (exact)
}

__global__ __launch_bounds__(NT, 3)
void costvol_kernel(const float* __restrict__ c1,
                    const float* __restrict__ warped,
                    const float* __restrict__ alphap,
                    float* __restrict__ out)
{
    const int u  = blockIdx.x * NT + threadIdx.x;
    const int g  = u % NG;
    const int dy = (u / NG) % MO;
    const int h  = (u / UPH) % NH;
    const int b  = u / (UPH * NH);

    const int w0 = g * WPT;
    const int hr = h + dy - SR;
    const bool vrow = (unsigned)hr < (unsigned)NH;
    const int hrc = vrow ? hr : (hr < 0 ? 0 : NH - 1);

    // four aligned 16B loads covering w0-4 .. w0+11; edge lanes clamp the
    // OOB load to a safe in-row column and zero it via mask.
    const int o0 = (g == 0)      ? 0  : (w0 - 4);
    const int o1 = w0;
    const int o2 = w0 + 4;
    const int o3 = (g == NG - 1) ? w0 : (w0 + 8);
    const float mA = (g == 0)      ? 0.0f : 1.0f;
    const float mB = (g == NG - 1) ? 0.0f : 1.0f;

    const float* wp = warped + (size_t)b * NC * HW + (size_t)hrc * NW;
    const float* cp = c1     + (size_t)b * NC * HW + (size_t)h   * NW + w0;

    float acc[MO][WPT];
#pragma unroll
    for (int i = 0; i < MO; ++i)
#pragma unroll
        for (int j = 0; j < WPT; ++j) acc[i][j] = 0.0f;

    // prologue: channel 0 in flight
    float4 u0 = *(const float4*)(wp + o0);
    float4 u1 = *(const float4*)(wp + o1);
    float4 u2 = *(const float4*)(wp + o2);
    float4 u3 = *(const float4*)(wp + o3);
    float4 a0 = *(const float4*)(cp);
    float4 a1 = *(const float4*)(cp + 4);

#pragma unroll 2
    for (int c = 0; c < NC; ++c) {
        const int cnx = (c + 1 < NC) ? (c + 1) : c;   // last iter re-loads (harmless)
        const float* wn = wp + (size_t)cnx * HW;
        const float* cn = cp + (size_t)cnx * HW;
        // issue next channel's loads now; they fly under this channel's FMAs
        const float4 n0 = *(const float4*)(wn + o0);
        const float4 n1 = *(const float4*)(wn + o1);
        const float4 n2 = *(const float4*)(wn + o2);
        const float4 n3 = *(const float4*)(wn + o3);
        const float4 b0 = *(const float4*)(cn);
        const float4 b1 = *(const float4*)(cn + 4);

        const float win[16] = {
            u0.x * mA, u0.y * mA, u0.z * mA, u0.w * mA,
            u1.x, u1.y, u1.z, u1.w,
            u2.x, u2.y, u2.z, u2.w,
            u3.x * mB, u3.y * mB, u3.z * mB, u3.w * mB };
        const float cv[WPT] = { a0.x, a0.y, a0.z, a0.w,
                                a1.x, a1.y, a1.z, a1.w };

#pragma unroll
        for (int dx = 0; dx < MO; ++dx)
#pragma unroll
            for (int j = 0; j < WPT; ++j)
                acc[dx][j] = fmaf(cv[j], win[j + dx], acc[dx][j]);

        u0 = n0; u1 = n1; u2 = n2; u3 = n3; a0 = b0; a1 = b1;
    }

    // epilogue: mean + leaky relu; invalid warped row -> exact zeros
    const float scale = 1.0f / (float)NC;
    const float al = alphap[0];
    float* op = out + ((size_t)b * (MO * MO) + (size_t)(dy * MO)) * HW
                    + (size_t)h * NW + w0;
#pragma unroll
    for (int dx = 0; dx < MO; ++dx) {
        float r[WPT];
#pragma unroll
        for (int j = 0; j < WPT; ++j) {
            const float vv = vrow ? acc[dx][j] * scale : 0.0f;
            r[j] = (vv >= 0.0f) ? vv : al * vv;
        }
        float4* q = (float4*)(op + (size_t)dx * HW);
        q[0] = make_float4(r[0], r[1], r[2], r[3]);
        q[1] = make_float4(r[4], r[5], r[6], r[7]);
    }
}

extern "C" void kernel_launch(void* const* d_in, const int* in_sizes, int n_in,
                              void* d_out, int out_size, void* d_ws, size_t ws_size,
                              hipStream_t stream) {
    (void)in_sizes; (void)n_in; (void)out_size; (void)d_ws; (void)ws_size;
    const float* c1     = (const float*)d_in[0];
    const float* warped = (const float*)d_in[1];
    const float* alpha  = (const float*)d_in[2];
    float* out          = (float*)d_out;
    costvol_kernel<<<dim3(NBLK), dim3(NT), 0, stream>>>(c1, warped, alpha, out);
}